// Round 2
// baseline (284.700 us; speedup 1.0000x reference)
//
#include <hip/hip_runtime.h>
#include <math.h>

#define D     64
#define NSLOT 8
#define NB    64
#define NROW  4096
#define EPS   1e-5f

// ---------------------------------------------------------------------------
// helpers
// ---------------------------------------------------------------------------
__device__ __forceinline__ float wredsum(float v) {
  #pragma unroll
  for (int m = 1; m < 64; m <<= 1) v += __shfl_xor(v, m);
  return v;
}

// y = W[row,:] . lvec  (64-long, lvec in LDS), via float4
__device__ __forceinline__ float matvec64(const float* __restrict__ W, int row,
                                          const float* lvec) {
  const float4* W4 = reinterpret_cast<const float4*>(W + row * D);
  const float4* v4 = reinterpret_cast<const float4*>(lvec);
  float acc = 0.f;
  #pragma unroll
  for (int e = 0; e < 16; ++e) {
    float4 w = W4[e];
    float4 v = v4[e];
    acc += w.x * v.x + w.y * v.y + w.z * v.z + w.w * v.w;
  }
  return acc;
}

// ---------------------------------------------------------------------------
// KA: the big per-iteration pass over x.
//   For each row n: LN(x_n) on the fly, logits vs 8 slots (q~, c), softmax
//   over slots, accumulate U[s][d] += a_s * xn_d and S[s] += a_s.
//   Block = 256 threads = 4 waves; wave handles 64 rows, 4 at a time
//   (16-lane group per row; lane owns 4 of the 64 d's). Global loads are
//   1024B contiguous per wave per iteration.
// ---------------------------------------------------------------------------
__global__ __launch_bounds__(256, 2)
void ka_kernel(const float* __restrict__ x,
               const float* __restrict__ qtil,
               const float* __restrict__ cvec,
               float* __restrict__ U, float* __restrict__ S) {
  const int b    = blockIdx.x >> 4;   // 16 row-blocks per batch
  const int rb   = blockIdx.x & 15;
  const int tid  = threadIdx.x;
  const int wave = tid >> 6;
  const int lane = tid & 63;
  const int c    = lane & 15;         // d-chunk index (4 floats)

  // q~ fragments and c offsets for this batch
  const float4* qt4 = reinterpret_cast<const float4*>(qtil + (size_t)b * NSLOT * D);
  float4 qf[NSLOT];
  float  cs[NSLOT];
  #pragma unroll
  for (int s = 0; s < NSLOT; ++s) {
    qf[s] = qt4[s * 16 + c];
    cs[s] = cvec[b * NSLOT + s];
  }

  float4 Ua[NSLOT];
  float  Sa[NSLOT];
  #pragma unroll
  for (int s = 0; s < NSLOT; ++s) { Ua[s] = make_float4(0.f, 0.f, 0.f, 0.f); Sa[s] = 0.f; }

  const float4* xb = reinterpret_cast<const float4*>(
      x + ((size_t)b * NROW + rb * 256 + wave * 64) * D);

  #pragma unroll 2
  for (int it = 0; it < 16; ++it) {
    float4 xv = xb[it * 64 + lane];  // 4 rows x 64 floats, fully coalesced

    // --- LayerNorm over the 16-lane group (row) ---
    float s1 = xv.x + xv.y + xv.z + xv.w;
    float s2 = xv.x * xv.x + xv.y * xv.y + xv.z * xv.z + xv.w * xv.w;
    #pragma unroll
    for (int m = 1; m < 16; m <<= 1) {
      s1 += __shfl_xor(s1, m);
      s2 += __shfl_xor(s2, m);
    }
    float mean = s1 * (1.f / 64.f);
    float var  = s2 * (1.f / 64.f) - mean * mean;
    float rstd = rsqrtf(var + EPS);
    float nb   = -mean * rstd;
    float4 xn;
    xn.x = fmaf(xv.x, rstd, nb);
    xn.y = fmaf(xv.y, rstd, nb);
    xn.z = fmaf(xv.z, rstd, nb);
    xn.w = fmaf(xv.w, rstd, nb);

    // --- logits: xn . q~_s (partials, then 16-lane butterfly) ---
    float p[NSLOT];
    #pragma unroll
    for (int s = 0; s < NSLOT; ++s)
      p[s] = xn.x * qf[s].x + xn.y * qf[s].y + xn.z * qf[s].z + xn.w * qf[s].w;
    #pragma unroll
    for (int m = 1; m < 16; m <<= 1) {
      #pragma unroll
      for (int s = 0; s < NSLOT; ++s) p[s] += __shfl_xor(p[s], m);
    }
    #pragma unroll
    for (int s = 0; s < NSLOT; ++s) p[s] += cs[s];

    // --- softmax over 8 slots (replicated in group; cheap) ---
    float mx = fmaxf(fmaxf(fmaxf(p[0], p[1]), fmaxf(p[2], p[3])),
                     fmaxf(fmaxf(p[4], p[5]), fmaxf(p[6], p[7])));
    float sum = 0.f;
    #pragma unroll
    for (int s = 0; s < NSLOT; ++s) {
      p[s] = exp2f((p[s] - mx) * 1.44269504f);
      sum += p[s];
    }
    float inv = 1.f / sum;
    #pragma unroll
    for (int s = 0; s < NSLOT; ++s) {
      float a = p[s] * inv + 1e-8f;
      Sa[s] += a;                       // one copy per lane of group (all equal)
      Ua[s].x = fmaf(a, xn.x, Ua[s].x); // lane's 4 d's: exact partials
      Ua[s].y = fmaf(a, xn.y, Ua[s].y);
      Ua[s].z = fmaf(a, xn.z, Ua[s].z);
      Ua[s].w = fmaf(a, xn.w, Ua[s].w);
    }
  }

  // cross-group reduce within wave (masks 16, 32): rows differ, chunks align.
  // Sa copies within a group are identical, so this sums the 4 distinct groups.
  #pragma unroll
  for (int m = 16; m < 64; m <<= 1) {
    #pragma unroll
    for (int s = 0; s < NSLOT; ++s) {
      Sa[s]   += __shfl_xor(Sa[s], m);
      Ua[s].x += __shfl_xor(Ua[s].x, m);
      Ua[s].y += __shfl_xor(Ua[s].y, m);
      Ua[s].z += __shfl_xor(Ua[s].z, m);
      Ua[s].w += __shfl_xor(Ua[s].w, m);
    }
  }

  __shared__ float lU[4][NSLOT][D];
  __shared__ float lS[4][NSLOT];
  if (lane < 16) {
    #pragma unroll
    for (int s = 0; s < NSLOT; ++s) {
      lU[wave][s][4 * c + 0] = Ua[s].x;
      lU[wave][s][4 * c + 1] = Ua[s].y;
      lU[wave][s][4 * c + 2] = Ua[s].z;
      lU[wave][s][4 * c + 3] = Ua[s].w;
    }
    if (c == 0) {
      #pragma unroll
      for (int s = 0; s < NSLOT; ++s) lS[wave][s] = Sa[s];
    }
  }
  __syncthreads();

  for (int cell = tid; cell < NSLOT * D; cell += 256) {
    int s = cell >> 6, d = cell & 63;
    atomicAdd(&U[((size_t)b * NSLOT + s) * D + d],
              lU[0][s][d] + lU[1][s][d] + lU[2][s][d] + lU[3][s][d]);
  }
  if (tid < NSLOT) {
    atomicAdd(&S[b * NSLOT + tid],
              lS[0][tid] + lS[1][tid] + lS[2][tid] + lS[3][tid]);
  }
}

// ---------------------------------------------------------------------------
// KB: per-batch slot update. Block = 1 batch, 8 waves (one per slot),
// lane = d. mode==0: init slots from mu+sigma*noise, zero U/S, compute q~.
// mode==1: updates=Wv@(U/S)+bv, GRU, LN, MLP; write slots (and d_out if
// last); compute q~ for the next iteration unless last. No __syncthreads
// needed: each wave touches only its own LDS rows.
// ---------------------------------------------------------------------------
__global__ __launch_bounds__(512)
void kb_kernel(int mode, int last,
               const float* __restrict__ noise, const float* __restrict__ mu,
               const float* __restrict__ sigma,
               const float* __restrict__ Wq, const float* __restrict__ bq,
               const float* __restrict__ Wk, const float* __restrict__ bk,
               const float* __restrict__ Wv, const float* __restrict__ bv,
               const float* __restrict__ Wih, const float* __restrict__ Whh,
               const float* __restrict__ bih, const float* __restrict__ bhh,
               const float* __restrict__ W1, const float* __restrict__ b1,
               const float* __restrict__ W2, const float* __restrict__ b2,
               float* __restrict__ slots, float* __restrict__ qtil,
               float* __restrict__ cvec, float* __restrict__ U,
               float* __restrict__ S, float* __restrict__ out) {
  const int b   = blockIdx.x;
  const int s   = threadIdx.x >> 6;
  const int d   = threadIdx.x & 63;
  const int idx = (b * NSLOT + s) * D + d;

  __shared__ float lA[NSLOT][D];
  __shared__ float lB[NSLOT][D];
  __shared__ float lhid[NSLOT][128];

  float h;
  if (mode == 0) {
    h = mu[d] + sigma[d] * noise[idx];
    U[idx] = 0.f;
    if (d == 0) S[b * NSLOT + s] = 0.f;
    slots[idx] = h;
  } else {
    float Uv = U[idx];
    float Ss = S[b * NSLOT + s];      // wave-uniform broadcast read
    U[idx] = 0.f;                     // zero for next iteration (after read)
    if (d == 0) S[b * NSLOT + s] = 0.f;
    float ub = Uv / Ss;

    lA[s][d] = ub;
    float upd = bv[d] + matvec64(Wv, d, lA[s]);

    h = slots[idx];
    lB[s][d] = h;
    lA[s][d] = upd;                   // reuse after Wv matvec has read lA

    float g0 = bih[d]       + matvec64(Wih, d,       lA[s]);
    float g1 = bih[64 + d]  + matvec64(Wih, 64 + d,  lA[s]);
    float g2 = bih[128 + d] + matvec64(Wih, 128 + d, lA[s]);
    float e0 = bhh[d]       + matvec64(Whh, d,       lB[s]);
    float e1 = bhh[64 + d]  + matvec64(Whh, 64 + d,  lB[s]);
    float e2 = bhh[128 + d] + matvec64(Whh, 128 + d, lB[s]);

    float r  = 1.f / (1.f + expf(-(g0 + e0)));
    float z  = 1.f / (1.f + expf(-(g1 + e1)));
    float nn = tanhf(g2 + r * e2);
    h = (1.f - z) * nn + z * h;

    // LayerNorm
    float m  = wredsum(h) * (1.f / 64.f);
    float hc = h - m;
    float v  = wredsum(hc * hc) * (1.f / 64.f);
    float sl = hc * rsqrtf(v + EPS);

    // MLP with residual
    lA[s][d] = sl;
    float a0 = b1[d]      + matvec64(W1, d,      lA[s]);
    float a1 = b1[64 + d] + matvec64(W1, 64 + d, lA[s]);
    lhid[s][d]      = fmaxf(a0, 0.f);
    lhid[s][64 + d] = fmaxf(a1, 0.f);
    float o = b2[d];
    {
      const float4* W24  = reinterpret_cast<const float4*>(W2 + d * 128);
      const float4* hid4 = reinterpret_cast<const float4*>(lhid[s]);
      #pragma unroll
      for (int e = 0; e < 32; ++e) {
        float4 w  = W24[e];
        float4 vv = hid4[e];
        o += w.x * vv.x + w.y * vv.y + w.z * vv.z + w.w * vv.w;
      }
    }
    h = sl + o;
    slots[idx] = h;
    if (last) out[idx] = h;
  }

  if (!last) {
    // q = LN(slots) @ Wq^T + bq ; q~ = scale*(q @ Wk) ; c = scale*(bk.q)
    float m  = wredsum(h) * (1.f / 64.f);
    float hc = h - m;
    float v  = wredsum(hc * hc) * (1.f / 64.f);
    float ln = hc * rsqrtf(v + EPS);

    lB[s][d] = ln;
    float q = bq[d] + matvec64(Wq, d, lB[s]);
    lA[s][d] = q;

    float qt = 0.f;
    #pragma unroll
    for (int e = 0; e < 64; ++e) qt = fmaf(lA[s][e], Wk[e * D + d], qt);

    const float sc = 0.125f;  // 1/sqrt(64)
    qtil[idx] = qt * sc;
    float ca = wredsum(bk[d] * q) * sc;
    if (d == 0) cvec[b * NSLOT + s] = ca;
  }
}

// ---------------------------------------------------------------------------
extern "C" void kernel_launch(void* const* d_in, const int* in_sizes, int n_in,
                              void* d_out, int out_size, void* d_ws, size_t ws_size,
                              hipStream_t stream) {
  (void)in_sizes; (void)n_in; (void)out_size; (void)ws_size;
  const float* x     = (const float*)d_in[0];
  const float* noise = (const float*)d_in[1];
  const float* Wq    = (const float*)d_in[2];
  const float* bq    = (const float*)d_in[3];
  const float* Wk    = (const float*)d_in[4];
  const float* bk    = (const float*)d_in[5];
  const float* Wv    = (const float*)d_in[6];
  const float* bv    = (const float*)d_in[7];
  const float* Wih   = (const float*)d_in[8];
  const float* Whh   = (const float*)d_in[9];
  const float* bih   = (const float*)d_in[10];
  const float* bhh   = (const float*)d_in[11];
  const float* W1    = (const float*)d_in[12];
  const float* b1    = (const float*)d_in[13];
  const float* W2    = (const float*)d_in[14];
  const float* b2    = (const float*)d_in[15];
  const float* mu    = (const float*)d_in[16];
  const float* sigma = (const float*)d_in[17];

  float* ws    = (float*)d_ws;
  float* slots = ws;          // 64*8*64 = 32768
  float* qtil  = ws + 32768;  // 32768
  float* cvec  = ws + 65536;  // 512
  float* U     = ws + 66048;  // 32768
  float* S     = ws + 98816;  // 512
  float* out   = (float*)d_out;

  auto launch_kb = [&](int mode, int last) {
    kb_kernel<<<NB, 512, 0, stream>>>(mode, last, noise, mu, sigma,
                                      Wq, bq, Wk, bk, Wv, bv,
                                      Wih, Whh, bih, bhh, W1, b1, W2, b2,
                                      slots, qtil, cvec, U, S, out);
  };

  launch_kb(0, 0);  // init slots, q~, zero U/S
  for (int it = 1; it <= 3; ++it) {
    ka_kernel<<<NB * 16, 256, 0, stream>>>(x, qtil, cvec, U, S);
    launch_kb(1, it == 3 ? 1 : 0);
  }
}